// Round 5
// baseline (204.899 us; speedup 1.0000x reference)
//
#include <hip/hip_runtime.h>

// LocalAutoCorr2D: out[b,iy,ix,c,dy,dx] =
//   sum_{u,v in [0,8)} x[b,c,4iy+u,4ix+v] * x[b,c,4iy+dy+u-4,4ix+dx+v-4]  (zero-padded)
//
// B=4 C=128 H=W=128, kh=kw=8, sh=sw=4, nh=nw=31.
// Block: 256 threads = 8 channels x (8x x 4y) positions. 38KB LDS + <=128 VGPR
// (pinned via amdgpu_waves_per_eu(4,4)) -> 4 blocks/CU = 4 waves/SIMD, no spills.
// Per-thread: 8x8 output register tile; base rows streamed from LDS; coalesced
// stores via LDS transpose (4 rounds of 8 positions).

#define Bn 4
#define Cn 128
#define Hn 128
#define Wn 128
#define NH 31
#define NW 31
#define CB 8             // channels per block
#define PXT 8            // x positions per block
#define PYT 4            // y positions per block
#define TROWS 27         // (PYT-1)*4 + 15
#define RST 44           // row stride in floats ((PXT-1)*4+15 = 43, pad to 44)
#define CST (TROWS*RST)  // 1188 floats per channel
#define F4C (TROWS*11)   // 297 float4 per channel
#define TPST 137         // transpose: f4 stride per position (137%8=1 -> spread)
#define TCST 17          // transpose: f4 stride per channel

__global__ __launch_bounds__(256)
__attribute__((amdgpu_waves_per_eu(4, 4)))
void lac_kernel(const float* __restrict__ x, float* __restrict__ out) {
    __shared__ float sm[CB * CST];   // 38,016 B -> 4 blocks/CU

    const int bid = blockIdx.x;
    const int ct = bid & 15;         // channel tile 0..15
    const int tx = (bid >> 4) & 3;   // x tile 0..3
    const int ty = (bid >> 6) & 7;   // y tile 0..7
    const int b  = bid >> 9;         // batch 0..3
    const int c0 = ct * CB;
    const int gy0 = ty * (PYT * 4) - 4;   // first staged global row
    const int gx0 = tx * (PXT * 4) - 4;   // first staged global col
    const int tid = threadIdx.x;

    // ---- stage region: CB channels x TROWS rows x 44 cols (float4, LDS-linear) ----
    for (int i = tid; i < CB * F4C; i += 256) {
        const int c   = i / F4C;
        const int rem = i - c * F4C;
        const int r   = rem / 11;
        const int q   = rem - r * 11;
        const int y   = gy0 + r;
        const int xc  = gx0 + q * 4;
        const float* src = x + (((size_t)(b * Cn + c0 + c) * Hn + y) * Wn + xc);
        float4 v;
        if (y >= 0 && y < Hn && xc >= 0 && xc + 3 < Wn) {
            v = *reinterpret_cast<const float4*>(src);
        } else if (y >= 0 && y < Hn) {
            v.x = (xc + 0 >= 0 && xc + 0 < Wn) ? src[0] : 0.0f;
            v.y = (xc + 1 >= 0 && xc + 1 < Wn) ? src[1] : 0.0f;
            v.z = (xc + 2 >= 0 && xc + 2 < Wn) ? src[2] : 0.0f;
            v.w = (xc + 3 >= 0 && xc + 3 < Wn) ? src[3] : 0.0f;
        } else {
            v = make_float4(0.0f, 0.0f, 0.0f, 0.0f);
        }
        reinterpret_cast<float4*>(sm)[i] = v;
    }
    __syncthreads();

    // ---- compute: thread = (channel cs, position px,py), 64 outputs in regs ----
    const int cs  = tid & 7;
    const int pos = tid >> 3;        // 0..31
    const int px  = pos & 7;
    const int py  = pos >> 3;        // 0..3
    const float* rg = &sm[cs * CST + (py * 4) * RST + px * 4];

    float acc[8][8];
#pragma unroll
    for (int i = 0; i < 8; ++i)
#pragma unroll
        for (int j = 0; j < 8; ++j) acc[i][j] = 0.0f;

#pragma unroll
    for (int r = 0; r < 15; ++r) {
        float rw[16];
        float4 q0 = *reinterpret_cast<const float4*>(&rg[r * RST + 0]);
        float4 q1 = *reinterpret_cast<const float4*>(&rg[r * RST + 4]);
        float4 q2 = *reinterpret_cast<const float4*>(&rg[r * RST + 8]);
        float4 q3 = *reinterpret_cast<const float4*>(&rg[r * RST + 12]);
        rw[0]  = q0.x; rw[1]  = q0.y; rw[2]  = q0.z; rw[3]  = q0.w;
        rw[4]  = q1.x; rw[5]  = q1.y; rw[6]  = q1.z; rw[7]  = q1.w;
        rw[8]  = q2.x; rw[9]  = q2.y; rw[10] = q2.z; rw[11] = q2.w;
        rw[12] = q3.x; rw[13] = q3.y; rw[14] = q3.z; rw[15] = q3.w;
#pragma unroll
        for (int u = 0; u < 8; ++u) {
            const int dy = r - u;           // compile-time after unroll
            if (dy >= 0 && dy < 8) {
                // stream base row u from LDS (region row u+4, cols 4..11; 16B-aligned)
                float4 b0 = *reinterpret_cast<const float4*>(&rg[(u + 4) * RST + 4]);
                float4 b1 = *reinterpret_cast<const float4*>(&rg[(u + 4) * RST + 8]);
                float bsr[8];
                bsr[0] = b0.x; bsr[1] = b0.y; bsr[2] = b0.z; bsr[3] = b0.w;
                bsr[4] = b1.x; bsr[5] = b1.y; bsr[6] = b1.z; bsr[7] = b1.w;
#pragma unroll
                for (int v = 0; v < 8; ++v) {
                    const float bv = bsr[v];
#pragma unroll
                    for (int dx = 0; dx < 8; ++dx)
                        acc[dy][dx] = fmaf(bv, rw[v + dx], acc[dy][dx]);
                }
            }
        }
    }

    // ---- coalesced store via LDS transpose: 4 rounds, one y-row (8 positions) each ----
    // round rnd handles py == rnd. Transpose layout (f4): [p(8)*TPST][c(8)*TCST][k(16)]
    float4* lds4 = reinterpret_cast<float4*>(sm);
#pragma unroll
    for (int rnd = 0; rnd < 4; ++rnd) {
        __syncthreads();
        if (py == rnd) {
            const int p = px;
#pragma unroll
            for (int dy = 0; dy < 8; ++dy) {
                lds4[p * TPST + cs * TCST + dy * 2 + 0] =
                    make_float4(acc[dy][0], acc[dy][1], acc[dy][2], acc[dy][3]);
                lds4[p * TPST + cs * TCST + dy * 2 + 1] =
                    make_float4(acc[dy][4], acc[dy][5], acc[dy][6], acc[dy][7]);
            }
        }
        __syncthreads();
        const int iy = ty * PYT + rnd;
        if (iy < NH) {
            // 8 positions x 128 f4 each; 256 threads store 1 f4 per sub-pass.
#pragma unroll
            for (int sp = 0; sp < 4; ++sp) {
                const int p  = sp * 2 + (tid >> 7);
                const int ix = tx * PXT + p;
                if (ix < NW) {
                    const int j = tid & 127;   // f4 index within (position) chunk
                    float4* obase = reinterpret_cast<float4*>(
                        out + ((((size_t)b * NH + iy) * NW + ix) * Cn + c0) * 64);
                    obase[j] = lds4[p * TPST + (j >> 4) * TCST + (j & 15)];
                }
            }
        }
    }
}

extern "C" void kernel_launch(void* const* d_in, const int* in_sizes, int n_in,
                              void* d_out, int out_size, void* d_ws, size_t ws_size,
                              hipStream_t stream) {
    const float* x = (const float*)d_in[0];
    float* out = (float*)d_out;
    // grid = B(4) * ty(8) * tx(4) * ct(16) = 2048 blocks
    lac_kernel<<<dim3(2048), dim3(256), 0, stream>>>(x, out);
}

// Round 6
// 101.357 us; speedup vs baseline: 2.0216x; 2.0216x over previous
//
#include <hip/hip_runtime.h>

// LocalAutoCorr2D: out[b,iy,ix,c,dy,dx] =
//   sum_{u,v in [0,8)} x[b,c,4iy+u,4ix+v] * x[b,c,4iy+dy+u-4,4ix+dx+v-4]  (zero-padded)
//
// B=4 C=128 H=W=128, kh=kw=8, sh=sw=4, nh=nw=31.
// Block: 256 threads = 4 ch x 8 px x 4 py x 2 dy-halves. Each thread computes
// acc[4][8] (one dy-half of one position) -> live set ~70 VGPR, no spills at
// ANY plausible RA allocation. 19KB LDS. XCD-chunked block swizzle for halo L2 reuse.

#define Cn 128
#define Hn 128
#define Wn 128
#define NH 31
#define NW 31
#define CB 4             // channels per block
#define PXT 8            // x positions per block
#define PYT 4            // y positions per block
#define TROWS 27         // (PYT-1)*4 + 15
#define RST 44           // floats per region row (43 used)
#define CST (TROWS*RST)  // 1188 floats per channel; 297 f4 (== 1 mod 8 -> bank spread)
#define F4C (TROWS*11)   // 297 float4 per channel
#define TCST 17          // transpose: f4 stride per channel
#define TPST (CB*TCST+1) // 69: f4 stride per position

__global__ __launch_bounds__(256, 2)
void lac_kernel(const float* __restrict__ x, float* __restrict__ out) {
    __shared__ float sm[CB * CST];   // 19,008 B

    // XCD-chunked swizzle: 4096 blocks, 512 consecutive logical ids per XCD.
    const int bid = blockIdx.x;
    const int lg = ((bid & 7) << 9) | (bid >> 3);
    const int tx = lg & 3;           // x tile 0..3
    const int ty = (lg >> 2) & 7;    // y tile 0..7
    const int ct = (lg >> 5) & 31;   // channel tile 0..31
    const int b  = lg >> 10;         // batch 0..3
    const int c0 = ct * CB;
    const int gy0 = ty * (PYT * 4) - 4;
    const int gx0 = tx * (PXT * 4) - 4;
    const int tid = threadIdx.x;

    // ---- stage region: CB channels x 27 rows x 44 cols (float4, LDS-linear) ----
    for (int i = tid; i < CB * F4C; i += 256) {
        const int c   = i / F4C;
        const int rem = i - c * F4C;
        const int r   = rem / 11;
        const int q   = rem - r * 11;
        const int y   = gy0 + r;
        const int xc  = gx0 + q * 4;
        const float* src = x + (((size_t)(b * Cn + c0 + c) * Hn + y) * Wn + xc);
        float4 v;
        if (y >= 0 && y < Hn && xc >= 0 && xc + 3 < Wn) {
            v = *reinterpret_cast<const float4*>(src);
        } else if (y >= 0 && y < Hn) {
            v.x = (xc + 0 >= 0 && xc + 0 < Wn) ? src[0] : 0.0f;
            v.y = (xc + 1 >= 0 && xc + 1 < Wn) ? src[1] : 0.0f;
            v.z = (xc + 2 >= 0 && xc + 2 < Wn) ? src[2] : 0.0f;
            v.w = (xc + 3 >= 0 && xc + 3 < Wn) ? src[3] : 0.0f;
        } else {
            v = make_float4(0.0f, 0.0f, 0.0f, 0.0f);
        }
        reinterpret_cast<float4*>(sm)[i] = v;
    }
    __syncthreads();

    // ---- compute: thread = (cs, px, py, half); acc[d][dx], dy = half*4+d ----
    const int cs   = tid & 3;
    const int px   = (tid >> 2) & 7;
    const int py   = (tid >> 5) & 3;
    const int half = tid >> 7;
    const float* rg  = &sm[cs * CST + (py * 4) * RST + px * 4];
    const float* rgr = rg + (half * 4) * RST;   // shifted-row base for this half

    float acc[4][8];
#pragma unroll
    for (int i = 0; i < 4; ++i)
#pragma unroll
        for (int j = 0; j < 8; ++j) acc[i][j] = 0.0f;

#pragma unroll
    for (int rr = 0; rr < 11; ++rr) {           // r = half*4 + rr
        float rw[16];
        float4 q0 = *reinterpret_cast<const float4*>(&rgr[rr * RST + 0]);
        float4 q1 = *reinterpret_cast<const float4*>(&rgr[rr * RST + 4]);
        float4 q2 = *reinterpret_cast<const float4*>(&rgr[rr * RST + 8]);
        float4 q3 = *reinterpret_cast<const float4*>(&rgr[rr * RST + 12]);
        rw[0]  = q0.x; rw[1]  = q0.y; rw[2]  = q0.z; rw[3]  = q0.w;
        rw[4]  = q1.x; rw[5]  = q1.y; rw[6]  = q1.z; rw[7]  = q1.w;
        rw[8]  = q2.x; rw[9]  = q2.y; rw[10] = q2.z; rw[11] = q2.w;
        rw[12] = q3.x; rw[13] = q3.y; rw[14] = q3.z; rw[15] = q3.w;
#pragma unroll
        for (int d = 0; d < 4; ++d) {
            const int u = rr - d;               // compile-time after unroll
            if (u >= 0 && u < 8) {
                // base row u: region row u+4, cols 4..11 (16B-aligned, half-independent)
                float4 b0 = *reinterpret_cast<const float4*>(&rg[(u + 4) * RST + 4]);
                float4 b1 = *reinterpret_cast<const float4*>(&rg[(u + 4) * RST + 8]);
                float bsr[8];
                bsr[0] = b0.x; bsr[1] = b0.y; bsr[2] = b0.z; bsr[3] = b0.w;
                bsr[4] = b1.x; bsr[5] = b1.y; bsr[6] = b1.z; bsr[7] = b1.w;
#pragma unroll
                for (int v = 0; v < 8; ++v) {
                    const float bv = bsr[v];
#pragma unroll
                    for (int dx = 0; dx < 8; ++dx)
                        acc[d][dx] = fmaf(bv, rw[v + dx], acc[d][dx]);
                }
            }
        }
    }

    // ---- coalesced store via LDS transpose: 4 rounds, one y-row (8 positions) each ----
    // transpose layout (f4): [p(8)*TPST][c(4)*TCST][k(16)], k = dy*2+q = half*8+d*2+q
    float4* lds4 = reinterpret_cast<float4*>(sm);
#pragma unroll
    for (int rnd = 0; rnd < 4; ++rnd) {
        __syncthreads();
        if (py == rnd) {
            const int wb = px * TPST + cs * TCST + half * 8;
#pragma unroll
            for (int d = 0; d < 4; ++d) {
                lds4[wb + d * 2 + 0] = make_float4(acc[d][0], acc[d][1], acc[d][2], acc[d][3]);
                lds4[wb + d * 2 + 1] = make_float4(acc[d][4], acc[d][5], acc[d][6], acc[d][7]);
            }
        }
        __syncthreads();
        const int iy = ty * PYT + rnd;
        if (iy < NH) {
            // 8 positions x 64 f4 chunks; each wave streams one 1KB-contiguous chunk.
#pragma unroll
            for (int sp = 0; sp < 2; ++sp) {
                const int p  = sp * 4 + (tid >> 6);
                const int ix = tx * PXT + p;
                if (ix < NW) {
                    const int j = tid & 63;     // f4 index within position chunk
                    float4* obase = reinterpret_cast<float4*>(
                        out + ((((size_t)b * NH + iy) * NW + ix) * Cn + c0) * 64);
                    obase[j] = lds4[p * TPST + (j >> 4) * TCST + (j & 15)];
                }
            }
        }
    }
}

extern "C" void kernel_launch(void* const* d_in, const int* in_sizes, int n_in,
                              void* d_out, int out_size, void* d_ws, size_t ws_size,
                              hipStream_t stream) {
    const float* x = (const float*)d_in[0];
    float* out = (float*)d_out;
    // grid = b(4) * ct(32) * ty(8) * tx(4) = 4096 blocks
    lac_kernel<<<dim3(4096), dim3(256), 0, stream>>>(x, out);
}

// Round 7
// 81.088 us; speedup vs baseline: 2.5269x; 1.2500x over previous
//
#include <hip/hip_runtime.h>

// LocalAutoCorr2D: out[b,iy,ix,c,dy,dx] =
//   sum_{u,v in [0,8)} x[b,c,4iy+u,4ix+v] * x[b,c,4iy+dy+u-4,4ix+dx+v-4]  (zero-padded)
//
// B=4 C=128 H=W=128, kh=kw=8, sh=sw=4, nh=nw=31.
// Block: 256 threads = 4 ch x 8 px x 4 py x 2 dy-halves; thread owns acc[4][8].
// KEY: base-window values are re-derived from the row sweep itself via a 4-slot
// rolling register cache (ks): half 0 sweeps rows DESCENDING (base rows ahead),
// half 1 ASCENDING (base rows behind) -> zero extra LDS reads for the base.
// 19.8KB LDS, ~92-reg live set -> no spills. XCD-chunked swizzle for L2 reuse.

#define Cn 128
#define Hn 128
#define Wn 128
#define NH 31
#define NW 31
#define CB 4             // channels per block
#define PXT 8            // x positions per block
#define PYT 4            // y positions per block
#define TROWS 27         // (PYT-1)*4 + 15
#define RST 44           // floats per region row (43 used)
#define CSTF4 310        // float4 per channel (297 used; 310%8=6 -> 2-way max aliasing)
#define F4C (TROWS*11)   // 297 float4 staged per channel
#define TCST 17          // transpose: f4 stride per channel
#define TPST (CB*TCST+1) // 69: f4 stride per position

__global__ __launch_bounds__(256, 2)
void lac_kernel(const float* __restrict__ x, float* __restrict__ out) {
    __shared__ float sm[CB * CSTF4 * 4];   // 19,840 B

    // XCD-chunked swizzle: 4096 blocks, 512 consecutive logical ids per XCD.
    const int bid = blockIdx.x;
    const int lg = ((bid & 7) << 9) | (bid >> 3);
    const int tx = lg & 3;           // x tile 0..3
    const int ty = (lg >> 2) & 7;    // y tile 0..7
    const int ct = (lg >> 5) & 31;   // channel tile 0..31
    const int b  = lg >> 10;         // batch 0..3
    const int c0 = ct * CB;
    const int gy0 = ty * (PYT * 4) - 4;
    const int gx0 = tx * (PXT * 4) - 4;
    const int tid = threadIdx.x;

    // ---- stage region: CB channels x 27 rows x 44 cols (float4) ----
    for (int i = tid; i < CB * F4C; i += 256) {
        const int c   = i / F4C;
        const int rem = i - c * F4C;
        const int r   = rem / 11;
        const int q   = rem - r * 11;
        const int y   = gy0 + r;
        const int xc  = gx0 + q * 4;
        const float* src = x + (((size_t)(b * Cn + c0 + c) * Hn + y) * Wn + xc);
        float4 v;
        if (y >= 0 && y < Hn && xc >= 0 && xc + 3 < Wn) {
            v = *reinterpret_cast<const float4*>(src);
        } else if (y >= 0 && y < Hn) {
            v.x = (xc + 0 >= 0 && xc + 0 < Wn) ? src[0] : 0.0f;
            v.y = (xc + 1 >= 0 && xc + 1 < Wn) ? src[1] : 0.0f;
            v.z = (xc + 2 >= 0 && xc + 2 < Wn) ? src[2] : 0.0f;
            v.w = (xc + 3 >= 0 && xc + 3 < Wn) ? src[3] : 0.0f;
        } else {
            v = make_float4(0.0f, 0.0f, 0.0f, 0.0f);
        }
        reinterpret_cast<float4*>(sm)[c * CSTF4 + r * 11 + q] = v;
    }
    __syncthreads();

    // ---- compute: thread = (cs, px, py, half); acc[d][dx], dy = half*4+d ----
    const int cs   = tid & 3;
    const int px   = (tid >> 2) & 7;
    const int py   = (tid >> 5) & 3;
    const int half = tid >> 7;                 // wave-uniform
    const float* rg = &sm[cs * (CSTF4 * 4) + (py * 4) * RST + px * 4];

    float acc[4][8];
#pragma unroll
    for (int i = 0; i < 4; ++i)
#pragma unroll
        for (int j = 0; j < 8; ++j) acc[i][j] = 0.0f;

    float ks[4][8];   // rolling cache: ks[row&3][v] = X[row][v+4] (cols 4..11)

#define LOAD_RW(R)                                                              \
    float rw[16];                                                               \
    {                                                                           \
        float4 q0 = *reinterpret_cast<const float4*>(&rg[(R) * RST + 0]);       \
        float4 q1 = *reinterpret_cast<const float4*>(&rg[(R) * RST + 4]);       \
        float4 q2 = *reinterpret_cast<const float4*>(&rg[(R) * RST + 8]);       \
        float4 q3 = *reinterpret_cast<const float4*>(&rg[(R) * RST + 12]);      \
        rw[0]=q0.x; rw[1]=q0.y; rw[2]=q0.z; rw[3]=q0.w;                         \
        rw[4]=q1.x; rw[5]=q1.y; rw[6]=q1.z; rw[7]=q1.w;                         \
        rw[8]=q2.x; rw[9]=q2.y; rw[10]=q2.z; rw[11]=q2.w;                       \
        rw[12]=q3.x; rw[13]=q3.y; rw[14]=q3.z; rw[15]=q3.w;                     \
    }

    if (half == 0) {
        // dy = d. Descending sweep R=11..0. At row R: shifted = rw (row R),
        // base row = R+4-d, cached in ks[(R-d)&3] (saved 4-d iters ago).
#pragma unroll
        for (int ii = 0; ii < 12; ++ii) {
            const int R = 11 - ii;
            LOAD_RW(R)
#pragma unroll
            for (int d = 0; d < 4; ++d) {
                if (R >= d && R <= 7 + d) {          // compile-time predicate
#pragma unroll
                    for (int v = 0; v < 8; ++v) {
                        const float bv = ks[(R - d) & 3][v];
#pragma unroll
                        for (int dx = 0; dx < 8; ++dx)
                            acc[d][dx] = fmaf(bv, rw[dx + v], acc[d][dx]);
                    }
                }
            }
#pragma unroll
            for (int v = 0; v < 8; ++v) ks[R & 3][v] = rw[4 + v];
        }
    } else {
        // dy = 4+d. Ascending sweep R=4..14. At row R: shifted = rw (row R),
        // base row = R-d: d=0 -> current rw[4..11], d>=1 -> ks[(R-d)&3].
#pragma unroll
        for (int ii = 0; ii < 11; ++ii) {
            const int R = 4 + ii;
            LOAD_RW(R)
#pragma unroll
            for (int d = 0; d < 4; ++d) {
                if (R >= 4 + d && R <= 11 + d) {     // compile-time predicate
#pragma unroll
                    for (int v = 0; v < 8; ++v) {
                        const float bv = (d == 0) ? rw[4 + v] : ks[(R - d) & 3][v];
#pragma unroll
                        for (int dx = 0; dx < 8; ++dx)
                            acc[d][dx] = fmaf(bv, rw[dx + v], acc[d][dx]);
                    }
                }
            }
#pragma unroll
            for (int v = 0; v < 8; ++v) ks[R & 3][v] = rw[4 + v];
        }
    }
#undef LOAD_RW

    // ---- coalesced store via LDS transpose: 4 rounds, one y-row (8 positions) each ----
    // transpose layout (f4): [p(8)*TPST][c(4)*TCST][k(16)], k = dy*2+q = half*8+d*2+q
    float4* lds4 = reinterpret_cast<float4*>(sm);
#pragma unroll
    for (int rnd = 0; rnd < 4; ++rnd) {
        __syncthreads();
        if (py == rnd) {
            const int wb = px * TPST + cs * TCST + half * 8;
#pragma unroll
            for (int d = 0; d < 4; ++d) {
                lds4[wb + d * 2 + 0] = make_float4(acc[d][0], acc[d][1], acc[d][2], acc[d][3]);
                lds4[wb + d * 2 + 1] = make_float4(acc[d][4], acc[d][5], acc[d][6], acc[d][7]);
            }
        }
        __syncthreads();
        const int iy = ty * PYT + rnd;
        if (iy < NH) {
            // 8 positions x 64 f4 chunks; each wave streams one 1KB-contiguous chunk.
#pragma unroll
            for (int sp = 0; sp < 2; ++sp) {
                const int p  = sp * 4 + (tid >> 6);
                const int ix = tx * PXT + p;
                if (ix < NW) {
                    const int j = tid & 63;     // f4 index within position chunk
                    float4* obase = reinterpret_cast<float4*>(
                        out + ((((size_t)b * NH + iy) * NW + ix) * Cn + c0) * 64);
                    obase[j] = lds4[p * TPST + (j >> 4) * TCST + (j & 15)];
                }
            }
        }
    }
}

extern "C" void kernel_launch(void* const* d_in, const int* in_sizes, int n_in,
                              void* d_out, int out_size, void* d_ws, size_t ws_size,
                              hipStream_t stream) {
    const float* x = (const float*)d_in[0];
    float* out = (float*)d_out;
    // grid = b(4) * ct(32) * ty(8) * tx(4) = 4096 blocks
    lac_kernel<<<dim3(4096), dim3(256), 0, stream>>>(x, out);
}